// Round 9
// baseline (741.366 us; speedup 1.0000x reference)
//
#include <hip/hip_runtime.h>
#include <hip/hip_bf16.h>

#define DDIM 128

typedef float    f32x16 __attribute__((ext_vector_type(16)));
typedef float    f32x4  __attribute__((ext_vector_type(4)));
typedef short    bf16x8 __attribute__((ext_vector_type(8)));
typedef __bf16   bf16x2t __attribute__((ext_vector_type(2)));
typedef unsigned u32x2  __attribute__((ext_vector_type(2)));
typedef unsigned u32x4  __attribute__((ext_vector_type(4)));
typedef unsigned short us4 __attribute__((ext_vector_type(4)));
typedef unsigned short us8 __attribute__((ext_vector_type(8)));

__device__ __forceinline__ unsigned pkbf(float a, float b) {
    bf16x2t v; v[0] = (__bf16)a; v[1] = (__bf16)b;
    return __builtin_bit_cast(unsigned, v);
}

__device__ __forceinline__ short f2bf16s(float a) {
    __bf16 b = (__bf16)a;
    return __builtin_bit_cast(short, b);
}

__device__ __forceinline__ float bf16tof(unsigned short u) {
    return __builtin_bit_cast(float, ((unsigned)u) << 16);
}

__device__ __forceinline__ bf16x8 cvt8(f32x4 a, f32x4 b) {
    u32x4 u = { pkbf(a[0],a[1]), pkbf(a[2],a[3]), pkbf(b[0],b[1]), pkbf(b[2],b[3]) };
    return __builtin_bit_cast(bf16x8, u);
}

__device__ __forceinline__ void plswap(unsigned &x, unsigned &y) {
    u32x2 r = __builtin_amdgcn_permlane32_swap(x, y, false, false);
    x = r[0]; y = r[1];
}

__device__ __forceinline__ float silu(float x) {
    return x * __builtin_amdgcn_rcpf(1.0f + __expf(-x));
}

// ---- kernel 0: FRAGMENT-MAJOR bf16 weights (layout verified R2-R8).
// W1frag: [s(24)][n(128)][hi(2)][k8(8)], col = 16*s + 8*hi + k8 of [W_e|W_s|W_d].
// W2frag: [s(8)][n(128)][hi(2)][k8(8)].
__global__ void prep_weights(const float* __restrict__ we, const float* __restrict__ wsrc,
                             const float* __restrict__ wdst, const float* __restrict__ wout,
                             short* __restrict__ w1frag, short* __restrict__ w2frag) {
    int tid = blockIdx.x * 256 + threadIdx.x;        // 65536 total
    if (tid < 24 * 128 * 16) {
        int k8 = tid & 7;
        int hi = (tid >> 3) & 1;
        int n  = (tid >> 4) & 127;
        int s  = tid >> 11;
        int col = 16 * s + 8 * hi + k8;              // 0..383
        const float* src = (col < 128) ? we : ((col < 256) ? wsrc : wdst);
        w1frag[tid] = f2bf16s(src[n * 128 + (col & 127)]);
    } else {
        int t2 = tid - 24 * 128 * 16;
        int k8 = t2 & 7;
        int hi = (t2 >> 3) & 1;
        int n  = (t2 >> 4) & 127;
        int s  = t2 >> 11;
        int col = 16 * s + 8 * hi + k8;              // 0..127
        w2frag[t2] = f2bf16s(wout[n * 128 + col]);
    }
}

// ---- node-table kernel (verified R5-R8): tbl[row] = feat[row] @ Wseg^T (bf16, no bias).
__global__ __launch_bounds__(256, 4) void node_table(
    const float* __restrict__ feat, const short* __restrict__ w1frag,
    int segoff, short* __restrict__ tbl, int N)
{
    const int tid  = threadIdx.x;
    const int wave = tid >> 6;
    const int lane = tid & 63;
    const int lo   = lane & 31;
    const int hi   = lane >> 5;
    const int base = blockIdx.x * 128 + wave * 32;
    const int row  = base + lo;
    const int rcl  = row < N ? row : N - 1;
    const float* pn = feat + (size_t)rcl * DDIM;
    const int coff  = 8 * hi;
    const int fslot = (lo * 2 + hi) * 8;

    f32x16 acc[4];
#pragma unroll
    for (int t = 0; t < 4; ++t)
#pragma unroll
        for (int r = 0; r < 16; ++r) acc[t][r] = 0.0f;

#pragma unroll
    for (int s = 0; s < 8; ++s) {
        const f32x4* pv = (const f32x4*)(pn + 16 * s + coff);
        f32x4 fa = pv[0], fb = pv[1];
        bf16x8 a = cvt8(fa, fb);
        const short* wb = w1frag + (segoff + s) * 2048 + fslot;
#pragma unroll
        for (int t = 0; t < 4; ++t) {
            bf16x8 w = *(const bf16x8*)(wb + t * 512);
            acc[t] = __builtin_amdgcn_mfma_f32_32x32x16_bf16(a, w, acc[t], 0, 0, 0);
        }
    }

#pragma unroll
    for (int r = 0; r < 16; ++r) {
        const int m = (r & 3) + 8 * (r >> 2) + 4 * hi;
        const int node = base + m;
        if (node < N) {
            short* po = tbl + (size_t)node * DDIM;
#pragma unroll
            for (int t = 0; t < 4; ++t)
                po[32 * t + lo] = f2bf16s(acc[t][r]);
        }
    }
}

// ---- R9 kernel: persistent pipelined edge GEMM.
// Weights (W_e slice + W2) + b0 staged in LDS once per block -> weight reads use
// lgkmcnt, fully decoupled from the vmcnt prefetch queue. Each wave grid-strides
// over 32-edge tiles with register double-buffered prefetch of idx/efeat/gathers.
__global__ __launch_bounds__(256, 2) void edge_kernel_pipe(
    const float* __restrict__ efeat, const short* __restrict__ tsrc,
    const short* __restrict__ tdst, const int* __restrict__ src_idx,
    const int* __restrict__ dst_idx, const float* __restrict__ b0,
    const float* __restrict__ b_out, const float* __restrict__ ln_g,
    const float* __restrict__ ln_b, const short* __restrict__ w1frag,
    const short* __restrict__ w2frag, float* __restrict__ out, int E)
{
    __shared__ __align__(16) short wlds[32768];   // [0..16K)=W_e frags (s=0..7), [16K..32K)=W2
    __shared__ __align__(16) float b0lds[128];

    const int tid = threadIdx.x;
    {
        const us8* s1 = (const us8*)w1frag;       // first 32KB of w1frag = W_e slice
        us8* d1 = (us8*)wlds;
        for (int i = tid; i < 2048; i += 256) d1[i] = s1[i];
        const us8* s2 = (const us8*)w2frag;
        us8* d2 = (us8*)(wlds + 16384);
        for (int i = tid; i < 2048; i += 256) d2[i] = s2[i];
        if (tid < 128) b0lds[tid] = b0[tid];
    }
    __syncthreads();

    const int lane = tid & 63;
    const int lo   = lane & 31;
    const int hi   = lane >> 5;
    const int coff  = 8 * hi;
    const int poff  = 4 * hi;
    const int fslot = (lo * 2 + hi) * 8;

    // tile-invariant per-lane params (col n = 32*tt + lo)
    float bov[4], gvw[4], bvw[4];
#pragma unroll
    for (int tt = 0; tt < 4; ++tt) {
        int n = 32 * tt + lo;
        bov[tt] = b_out[n]; gvw[tt] = ln_g[n]; bvw[tt] = ln_b[n];
    }

    const int wid = (blockIdx.x * 256 + tid) >> 6;
    const int nw  = (gridDim.x * 256) >> 6;
    int base = wid * 32;
    if (base >= E) return;
    const int stride = nw * 32;

    f32x4 faA[8], fbA[8], faB[8], fbB[8];
    us4  tsA[16], tdA[16], tsB[16], tdB[16];

    auto load_idx = [&](int tb, int& si, int& di) {
        int ec = tb + lo; if (ec >= E) ec = E - 1;
        si = src_idx[ec]; di = dst_idx[ec];
    };
    auto load_efeat = [&](int tb, f32x4 (&fa)[8], f32x4 (&fb)[8]) {
        int ec = tb + lo; if (ec >= E) ec = E - 1;
        const float* pe = efeat + (size_t)ec * DDIM;
#pragma unroll
        for (int s = 0; s < 8; ++s) {
            const f32x4* pv = (const f32x4*)(pe + 16 * s + coff);
            fa[s] = __builtin_nontemporal_load(pv);
            fb[s] = __builtin_nontemporal_load(pv + 1);
        }
    };
    auto load_gather = [&](int si, int di, us4 (&ts)[16], us4 (&td)[16]) {
        const short* prs = tsrc + (size_t)si * DDIM;
        const short* prd = tdst + (size_t)di * DDIM;
#pragma unroll
        for (int t = 0; t < 4; ++t)
#pragma unroll
            for (int Q = 0; Q < 4; ++Q) {
                const int c = 32 * t + 8 * Q + poff;
                ts[t * 4 + Q] = *(const us4*)(prs + c);
                td[t * 4 + Q] = *(const us4*)(prd + c);
            }
    };

    auto do_tile = [&](int tb,
                       f32x4 (&fa)[8], f32x4 (&fb)[8], us4 (&ts)[16], us4 (&td)[16],
                       int nb,
                       f32x4 (&xfa)[8], f32x4 (&xfb)[8], us4 (&xts)[16], us4 (&xtd)[16],
                       bool pref) {
        // ---- prefetch next tile's idx + efeat (stays in flight through this tile) ----
        int nsi = 0, ndi = 0;
        if (pref) { load_idx(nb, nsi, ndi); load_efeat(nb, xfa, xfb); }

        // ---- GEMM1 (transposed): acc init from b0 (LDS broadcast) ----
        f32x16 acc[4];
#pragma unroll
        for (int t = 0; t < 4; ++t)
#pragma unroll
            for (int Q = 0; Q < 4; ++Q) {
                f32x4 bq = *(const f32x4*)(b0lds + 32 * t + 8 * Q + poff);
                acc[t][4*Q+0] = bq[0]; acc[t][4*Q+1] = bq[1];
                acc[t][4*Q+2] = bq[2]; acc[t][4*Q+3] = bq[3];
            }

#pragma unroll
        for (int s = 0; s < 8; ++s) {
            bf16x8 x = cvt8(fa[s], fb[s]);               // B-frag: efeat[edge lo][16s+8hi+j]
            const short* wb = wlds + s * 2048 + fslot;   // A-frag from LDS (lgkmcnt)
#pragma unroll
            for (int t = 0; t < 4; ++t) {
                bf16x8 w = *(const bf16x8*)(wb + t * 512);
                acc[t] = __builtin_amdgcn_mfma_f32_32x32x16_bf16(w, x, acc[t], 0, 0, 0);
            }
        }

        // ---- prefetch next tile's gathers (idx has had GEMM1 to land) ----
        if (pref) load_gather(nsi, ndi, xts, xtd);

        // ---- add gathered table rows (lane-local; c = 32t+8Q+4hi+j) ----
#pragma unroll
        for (int t = 0; t < 4; ++t)
#pragma unroll
            for (int Q = 0; Q < 4; ++Q) {
                us4 a = ts[t * 4 + Q], d = td[t * 4 + Q];
#pragma unroll
                for (int j = 0; j < 4; ++j)
                    acc[t][4*Q+j] += bf16tof(a[j]) + bf16tof(d[j]);
            }

        // ---- SiLU + pack to bf16, lane-local ----
        unsigned hbf[4][4][2];
#pragma unroll
        for (int t = 0; t < 4; ++t)
#pragma unroll
            for (int Q = 0; Q < 4; ++Q) {
                float h0 = silu(acc[t][4*Q+0]), h1 = silu(acc[t][4*Q+1]);
                float h2 = silu(acc[t][4*Q+2]), h3 = silu(acc[t][4*Q+3]);
                hbf[t][Q][0] = pkbf(h0, h1);
                hbf[t][Q][1] = pkbf(h2, h3);
            }

        // ---- GEMM2 (straight): y = silu(h) @ W2^T, weights from LDS ----
        f32x16 acc2[4];
#pragma unroll
        for (int tt = 0; tt < 4; ++tt)
#pragma unroll
            for (int r = 0; r < 16; ++r) acc2[tt][r] = bov[tt];

#pragma unroll
        for (int s = 0; s < 8; ++s) {
            const int t  = s >> 1;
            const int q0 = (2 * s) & 3;
            const int q1 = q0 + 1;
            unsigned X0 = hbf[t][q0][0], X1 = hbf[t][q0][1];
            unsigned Y0 = hbf[t][q1][0], Y1 = hbf[t][q1][1];
            plswap(X0, Y0);
            plswap(X1, Y1);
            u32x4 fv = { X0, X1, Y0, Y1 };       // A-frag: h[edge lo][16s+8hi + 0..7]
            bf16x8 hf = __builtin_bit_cast(bf16x8, fv);
            const short* wb = wlds + 16384 + s * 2048 + fslot;
#pragma unroll
            for (int tt = 0; tt < 4; ++tt) {
                bf16x8 w = *(const bf16x8*)(wb + tt * 512);
                acc2[tt] = __builtin_amdgcn_mfma_f32_32x32x16_bf16(hf, w, acc2[tt], 0, 0, 0);
            }
        }

        // ---- LayerNorm (butterfly over 32 lanes) + coalesced NT store ----
#pragma unroll
        for (int r = 0; r < 16; ++r) {
            float s1 = acc2[0][r] + acc2[1][r] + acc2[2][r] + acc2[3][r];
            float s2 = acc2[0][r]*acc2[0][r] + acc2[1][r]*acc2[1][r]
                     + acc2[2][r]*acc2[2][r] + acc2[3][r]*acc2[3][r];
#pragma unroll
            for (int msk = 1; msk < 32; msk <<= 1) {
                s1 += __shfl_xor(s1, msk, 64);
                s2 += __shfl_xor(s2, msk, 64);
            }
            const float mu   = s1 * (1.0f / 128.0f);
            const float var  = s2 * (1.0f / 128.0f) - mu * mu;
            const float rstd = rsqrtf(var + 1e-5f);
            const int   m    = (r & 3) + 8 * (r >> 2) + 4 * hi;
            const int   eo   = tb + m;
            if (eo < E) {
                float* po = out + (size_t)eo * DDIM;
#pragma unroll
                for (int tt = 0; tt < 4; ++tt) {
                    float o = (acc2[tt][r] - mu) * rstd * gvw[tt] + bvw[tt];
                    __builtin_nontemporal_store(o, po + 32 * tt + lo);
                }
            }
        }
    };

    // prologue: fully load first tile into A
    {
        int si, di;
        load_idx(base, si, di);
        load_efeat(base, faA, fbA);
        load_gather(si, di, tsA, tdA);
    }

    int b = base;
    for (;;) {
        int nb = b + stride;
        do_tile(b, faA, fbA, tsA, tdA, nb, faB, fbB, tsB, tdB, nb < E);
        if (nb >= E) break;
        b = nb; nb = b + stride;
        do_tile(b, faB, fbB, tsB, tdB, nb, faA, fbA, tsA, tdA, nb < E);
        if (nb >= E) break;
        b = nb;
    }
}

// ---- deep fallback (R4-verified): full-K kernel, no workspace tables ----
__global__ __launch_bounds__(256, 4) void edge_kernel_fullk(
    const float* __restrict__ efeat, const float* __restrict__ src_feat,
    const float* __restrict__ dst_feat, const int* __restrict__ src_idx,
    const int* __restrict__ dst_idx, const float* __restrict__ b0,
    const float* __restrict__ b_out, const float* __restrict__ ln_g,
    const float* __restrict__ ln_b, const short* __restrict__ w1frag,
    const short* __restrict__ w2frag, float* __restrict__ out, int E)
{
    const int tid  = threadIdx.x;
    const int wave = tid >> 6;
    const int lane = tid & 63;
    const int lo   = lane & 31;
    const int hi   = lane >> 5;
    const int ebase = blockIdx.x * 128 + wave * 32;

    const int erow = ebase + lo;
    const int ecl  = erow < E ? erow : E - 1;
    const int sidx = src_idx[ecl];
    const int didx = dst_idx[ecl];
    const float* pe = efeat    + (size_t)ecl  * DDIM;
    const float* ps = src_feat + (size_t)sidx * DDIM;
    const float* pd = dst_feat + (size_t)didx * DDIM;

    const int coff  = 8 * hi;
    const int poff  = 4 * hi;
    const int fslot = (lo * 2 + hi) * 8;

    float bov[4], gv[4], bv[4];
#pragma unroll
    for (int tt = 0; tt < 4; ++tt) {
        int n = 32 * tt + lo;
        bov[tt] = b_out[n]; gv[tt] = ln_g[n]; bv[tt] = ln_b[n];
    }

    f32x16 acc[4];
#pragma unroll
    for (int t = 0; t < 4; ++t)
#pragma unroll
        for (int Q = 0; Q < 4; ++Q) {
            f32x4 bq = *(const f32x4*)(b0 + 32 * t + 8 * Q + poff);
            acc[t][4*Q+0] = bq[0]; acc[t][4*Q+1] = bq[1];
            acc[t][4*Q+2] = bq[2]; acc[t][4*Q+3] = bq[3];
        }

#pragma unroll
    for (int seg = 0; seg < 3; ++seg) {
        const float* p = (seg == 0) ? pe : ((seg == 1) ? ps : pd);
#pragma unroll
        for (int ks = 0; ks < 8; ++ks) {
            const f32x4* pv = (const f32x4*)(p + 16 * ks + coff);
            f32x4 fa, fb;
            if (seg == 0) { fa = __builtin_nontemporal_load(pv); fb = __builtin_nontemporal_load(pv + 1); }
            else          { fa = pv[0];                          fb = pv[1]; }
            bf16x8 x = cvt8(fa, fb);
            const int s = seg * 8 + ks;
            const short* wb = w1frag + s * 2048 + fslot;
#pragma unroll
            for (int t = 0; t < 4; ++t) {
                bf16x8 w = *(const bf16x8*)(wb + t * 512);
                acc[t] = __builtin_amdgcn_mfma_f32_32x32x16_bf16(w, x, acc[t], 0, 0, 0);
            }
        }
    }

    unsigned hbf[4][4][2];
#pragma unroll
    for (int t = 0; t < 4; ++t)
#pragma unroll
        for (int Q = 0; Q < 4; ++Q) {
            float h0 = silu(acc[t][4*Q+0]), h1 = silu(acc[t][4*Q+1]);
            float h2 = silu(acc[t][4*Q+2]), h3 = silu(acc[t][4*Q+3]);
            hbf[t][Q][0] = pkbf(h0, h1);
            hbf[t][Q][1] = pkbf(h2, h3);
        }

    f32x16 acc2[4];
#pragma unroll
    for (int tt = 0; tt < 4; ++tt)
#pragma unroll
        for (int r = 0; r < 16; ++r) acc2[tt][r] = bov[tt];

#pragma unroll
    for (int s = 0; s < 8; ++s) {
        const int t  = s >> 1;
        const int q0 = (2 * s) & 3;
        const int q1 = q0 + 1;
        unsigned X0 = hbf[t][q0][0], X1 = hbf[t][q0][1];
        unsigned Y0 = hbf[t][q1][0], Y1 = hbf[t][q1][1];
        plswap(X0, Y0);
        plswap(X1, Y1);
        u32x4 fv = { X0, X1, Y0, Y1 };
        bf16x8 hf = __builtin_bit_cast(bf16x8, fv);
        const short* wb = w2frag + s * 2048 + fslot;
#pragma unroll
        for (int tt = 0; tt < 4; ++tt) {
            bf16x8 w = *(const bf16x8*)(wb + tt * 512);
            acc2[tt] = __builtin_amdgcn_mfma_f32_32x32x16_bf16(hf, w, acc2[tt], 0, 0, 0);
        }
    }

#pragma unroll
    for (int r = 0; r < 16; ++r) {
        float s1 = acc2[0][r] + acc2[1][r] + acc2[2][r] + acc2[3][r];
        float s2 = acc2[0][r]*acc2[0][r] + acc2[1][r]*acc2[1][r]
                 + acc2[2][r]*acc2[2][r] + acc2[3][r]*acc2[3][r];
#pragma unroll
        for (int msk = 1; msk < 32; msk <<= 1) {
            s1 += __shfl_xor(s1, msk, 64);
            s2 += __shfl_xor(s2, msk, 64);
        }
        const float mu   = s1 * (1.0f / 128.0f);
        const float var  = s2 * (1.0f / 128.0f) - mu * mu;
        const float rstd = rsqrtf(var + 1e-5f);
        const int   m    = (r & 3) + 8 * (r >> 2) + 4 * hi;
        const int   eo   = ebase + m;
        if (eo < E) {
            float* po = out + (size_t)eo * DDIM;
#pragma unroll
            for (int tt = 0; tt < 4; ++tt) {
                float o = (acc2[tt][r] - mu) * rstd * gv[tt] + bv[tt];
                __builtin_nontemporal_store(o, po + 32 * tt + lo);
            }
        }
    }
}

extern "C" void kernel_launch(void* const* d_in, const int* in_sizes, int n_in,
                              void* d_out, int out_size, void* d_ws, size_t ws_size,
                              hipStream_t stream)
{
    const float* efeat    = (const float*)d_in[0];
    const float* src_feat = (const float*)d_in[1];
    const float* dst_feat = (const float*)d_in[2];
    const int*   src_idx  = (const int*)d_in[3];
    const int*   dst_idx  = (const int*)d_in[4];
    const float* w_efeat  = (const float*)d_in[5];
    const float* w_src    = (const float*)d_in[6];
    const float* w_dst    = (const float*)d_in[7];
    const float* b0       = (const float*)d_in[8];
    const float* w_out    = (const float*)d_in[9];
    const float* b_out    = (const float*)d_in[10];
    const float* ln_g     = (const float*)d_in[11];
    const float* ln_b     = (const float*)d_in[12];
    float* out = (float*)d_out;
    const int E    = in_sizes[3];
    const int nsrc = in_sizes[1] / DDIM;
    const int ndst = in_sizes[2] / DDIM;

    short* w1frag = (short*)d_ws;                              // 96 KB
    short* w2frag = (short*)((char*)d_ws + 24 * 128 * 16 * 2); // 32 KB
    const size_t tab_off  = 128 * 1024;
    const size_t need_tab = tab_off + ((size_t)nsrc + (size_t)ndst) * DDIM * 2;

    prep_weights<<<256, 256, 0, stream>>>(w_efeat, w_src, w_dst, w_out, w1frag, w2frag);

    if (ws_size >= need_tab) {
        short* tsrc = (short*)((char*)d_ws + tab_off);
        short* tdst = tsrc + (size_t)nsrc * DDIM;
        node_table<<<(nsrc + 127) / 128, 256, 0, stream>>>(src_feat, w1frag, 8,  tsrc, nsrc);
        node_table<<<(ndst + 127) / 128, 256, 0, stream>>>(dst_feat, w1frag, 16, tdst, ndst);
        // persistent pipelined kernel: 2 blocks/CU co-resident
        edge_kernel_pipe<<<512, 256, 0, stream>>>(efeat, tsrc, tdst, src_idx, dst_idx,
                                                  b0, b_out, ln_g, ln_b, w1frag, w2frag, out, E);
    } else {
        const int nb = (E + 127) / 128;
        edge_kernel_fullk<<<nb, 256, 0, stream>>>(efeat, src_feat, dst_feat, src_idx, dst_idx,
                                                  b0, b_out, ln_g, ln_b, w1frag, w2frag, out, E);
    }
}

// Round 10
// 712.600 us; speedup vs baseline: 1.0404x; 1.0404x over previous
//
#include <hip/hip_runtime.h>
#include <hip/hip_bf16.h>

#define DDIM 128

typedef float    f32x16 __attribute__((ext_vector_type(16)));
typedef float    f32x4  __attribute__((ext_vector_type(4)));
typedef short    bf16x8 __attribute__((ext_vector_type(8)));
typedef __bf16   bf16x2t __attribute__((ext_vector_type(2)));
typedef unsigned u32x2  __attribute__((ext_vector_type(2)));
typedef unsigned u32x4  __attribute__((ext_vector_type(4)));
typedef unsigned short us4 __attribute__((ext_vector_type(4)));
typedef unsigned short us8 __attribute__((ext_vector_type(8)));

__device__ __forceinline__ unsigned pkbf(float a, float b) {
    bf16x2t v; v[0] = (__bf16)a; v[1] = (__bf16)b;
    return __builtin_bit_cast(unsigned, v);
}

__device__ __forceinline__ short f2bf16s(float a) {
    __bf16 b = (__bf16)a;
    return __builtin_bit_cast(short, b);
}

__device__ __forceinline__ float bf16tof(unsigned short u) {
    return __builtin_bit_cast(float, ((unsigned)u) << 16);
}

__device__ __forceinline__ bf16x8 cvt8(f32x4 a, f32x4 b) {
    u32x4 u = { pkbf(a[0],a[1]), pkbf(a[2],a[3]), pkbf(b[0],b[1]), pkbf(b[2],b[3]) };
    return __builtin_bit_cast(bf16x8, u);
}

__device__ __forceinline__ void plswap(unsigned &x, unsigned &y) {
    u32x2 r = __builtin_amdgcn_permlane32_swap(x, y, false, false);
    x = r[0]; y = r[1];
}

__device__ __forceinline__ float silu(float x) {
    return x * __builtin_amdgcn_rcpf(1.0f + __expf(-x));
}

// ---- kernel 0: FRAGMENT-MAJOR bf16 weights (layout verified R2-R9).
// W1frag: [s(24)][n(128)][hi(2)][k8(8)], col = 16*s + 8*hi + k8 of [W_e|W_s|W_d].
// W2frag: [s(8)][n(128)][hi(2)][k8(8)].
__global__ void prep_weights(const float* __restrict__ we, const float* __restrict__ wsrc,
                             const float* __restrict__ wdst, const float* __restrict__ wout,
                             short* __restrict__ w1frag, short* __restrict__ w2frag) {
    int tid = blockIdx.x * 256 + threadIdx.x;        // 65536 total
    if (tid < 24 * 128 * 16) {
        int k8 = tid & 7;
        int hi = (tid >> 3) & 1;
        int n  = (tid >> 4) & 127;
        int s  = tid >> 11;
        int col = 16 * s + 8 * hi + k8;              // 0..383
        const float* src = (col < 128) ? we : ((col < 256) ? wsrc : wdst);
        w1frag[tid] = f2bf16s(src[n * 128 + (col & 127)]);
    } else {
        int t2 = tid - 24 * 128 * 16;
        int k8 = t2 & 7;
        int hi = (t2 >> 3) & 1;
        int n  = (t2 >> 4) & 127;
        int s  = t2 >> 11;
        int col = 16 * s + 8 * hi + k8;              // 0..127
        w2frag[t2] = f2bf16s(wout[n * 128 + col]);
    }
}

// ---- node-table kernel (verified R5-R9): tbl[row] = feat[row] @ Wseg^T (bf16, no bias).
__global__ __launch_bounds__(256, 4) void node_table(
    const float* __restrict__ feat, const short* __restrict__ w1frag,
    int segoff, short* __restrict__ tbl, int N)
{
    const int tid  = threadIdx.x;
    const int wave = tid >> 6;
    const int lane = tid & 63;
    const int lo   = lane & 31;
    const int hi   = lane >> 5;
    const int base = blockIdx.x * 128 + wave * 32;
    const int row  = base + lo;
    const int rcl  = row < N ? row : N - 1;
    const float* pn = feat + (size_t)rcl * DDIM;
    const int coff  = 8 * hi;
    const int fslot = (lo * 2 + hi) * 8;

    f32x16 acc[4];
#pragma unroll
    for (int t = 0; t < 4; ++t)
#pragma unroll
        for (int r = 0; r < 16; ++r) acc[t][r] = 0.0f;

#pragma unroll
    for (int s = 0; s < 8; ++s) {
        const f32x4* pv = (const f32x4*)(pn + 16 * s + coff);
        f32x4 fa = pv[0], fb = pv[1];
        bf16x8 a = cvt8(fa, fb);
        const short* wb = w1frag + (segoff + s) * 2048 + fslot;
#pragma unroll
        for (int t = 0; t < 4; ++t) {
            bf16x8 w = *(const bf16x8*)(wb + t * 512);
            acc[t] = __builtin_amdgcn_mfma_f32_32x32x16_bf16(a, w, acc[t], 0, 0, 0);
        }
    }

#pragma unroll
    for (int r = 0; r < 16; ++r) {
        const int m = (r & 3) + 8 * (r >> 2) + 4 * hi;
        const int node = base + m;
        if (node < N) {
            short* po = tbl + (size_t)node * DDIM;
#pragma unroll
            for (int t = 0; t < 4; ++t)
                po[32 * t + lo] = f2bf16s(acc[t][r]);
        }
    }
}

// ---- R10: persistent single-buffer pipelined edge kernel.
// Weights + biases in LDS (lgkmcnt) -> the vmcnt queue carries ONLY next-tile
// prefetch (idx, efeat, gathers) + stores. Each buffer is refilled immediately
// after its last use, so the long silu/GEMM2/LN/store phase overlaps the
// next tile's 32 KB of loads. No double buffers -> no spills.
__global__ __launch_bounds__(256, 2) void edge_pipe(
    const float* __restrict__ efeat, const short* __restrict__ tsrc,
    const short* __restrict__ tdst, const int* __restrict__ src_idx,
    const int* __restrict__ dst_idx, const float* __restrict__ b0,
    const float* __restrict__ b_out, const float* __restrict__ ln_g,
    const float* __restrict__ ln_b, const short* __restrict__ w1frag,
    const short* __restrict__ w2frag, float* __restrict__ out, int E)
{
    __shared__ __align__(16) short wlds[32768];   // [0..16K) shorts = W_e frags, [16K..32K) = W2
    __shared__ __align__(16) float b0l[128], bol[128], gl[128], bl[128];

    const int tid = threadIdx.x;
    {
        const us8* s1 = (const us8*)w1frag;       // first 32 KB of w1frag = W_e slice (s=0..7)
        us8* d1 = (us8*)wlds;
        for (int i = tid; i < 2048; i += 256) d1[i] = s1[i];
        const us8* s2 = (const us8*)w2frag;
        us8* d2 = (us8*)(wlds + 16384);
        for (int i = tid; i < 2048; i += 256) d2[i] = s2[i];
        if (tid < 128) {
            b0l[tid] = b0[tid];  bol[tid] = b_out[tid];
            gl[tid]  = ln_g[tid]; bl[tid] = ln_b[tid];
        }
    }
    __syncthreads();

    const int lane = tid & 63;
    const int lo   = lane & 31;
    const int hi   = lane >> 5;
    const int coff  = 8 * hi;
    const int poff  = 4 * hi;
    const int fslot = (lo * 2 + hi) * 8;

    const int wid = (blockIdx.x * 256 + tid) >> 6;
    const int nw  = (gridDim.x * 256) >> 6;
    int tb = wid * 32;
    if (tb >= E) return;                 // after barrier: safe
    const int stride = nw * 32;

    // ---- persistent buffers (single set) ----
    f32x4 fa[8], fb[8];
    us4  gs[16], gd[16];

    // prologue: fill buffers for first tile
    {
        int ec = tb + lo; if (ec >= E) ec = E - 1;
        int si = src_idx[ec], di = dst_idx[ec];
        const float* pe = efeat + (size_t)ec * DDIM;
#pragma unroll
        for (int s = 0; s < 8; ++s) {
            const f32x4* pv = (const f32x4*)(pe + 16 * s + coff);
            fa[s] = __builtin_nontemporal_load(pv);
            fb[s] = __builtin_nontemporal_load(pv + 1);
        }
        const short* prs = tsrc + (size_t)si * DDIM;
        const short* prd = tdst + (size_t)di * DDIM;
#pragma unroll
        for (int t = 0; t < 4; ++t)
#pragma unroll
            for (int Q = 0; Q < 4; ++Q) {
                const int c = 32 * t + 8 * Q + poff;
                gs[t * 4 + Q] = *(const us4*)(prs + c);
                gd[t * 4 + Q] = *(const us4*)(prd + c);
            }
    }

    for (;;) {
        const int nt = tb + stride;
        const bool hasnext = nt < E;
        const int pn = hasnext ? nt : tb;          // clamped prefetch target

        // ---- 1. issue next idx (oldest in this iteration's queue) ----
        int ecn = pn + lo; if (ecn >= E) ecn = E - 1;
        const int nsi = src_idx[ecn];
        const int ndi = dst_idx[ecn];
        const float* pen = efeat + (size_t)ecn * DDIM;

        // ---- 2. GEMM1 (transposed, LDS weights) with in-place efeat refill ----
        f32x16 acc[4];
#pragma unroll
        for (int t = 0; t < 4; ++t)
#pragma unroll
            for (int r = 0; r < 16; ++r) acc[t][r] = 0.0f;

#pragma unroll
        for (int s = 0; s < 8; ++s) {
            bf16x8 x = cvt8(fa[s], fb[s]);         // consume current
            const f32x4* pv = (const f32x4*)(pen + 16 * s + coff);
            fa[s] = __builtin_nontemporal_load(pv); // refill for next tile
            fb[s] = __builtin_nontemporal_load(pv + 1);
            const short* wb = wlds + s * 2048 + fslot;
#pragma unroll
            for (int t = 0; t < 4; ++t) {
                bf16x8 w = *(const bf16x8*)(wb + t * 512);
                acc[t] = __builtin_amdgcn_mfma_f32_32x32x16_bf16(w, x, acc[t], 0, 0, 0);
            }
        }
        __builtin_amdgcn_sched_barrier(0);         // pin refill issues above

        // ---- 3. add b0 + gathered rows (consume gs/gd) ----
#pragma unroll
        for (int t = 0; t < 4; ++t)
#pragma unroll
            for (int Q = 0; Q < 4; ++Q) {
                f32x4 bq = *(const f32x4*)(b0l + 32 * t + 8 * Q + poff);
                us4 a = gs[t * 4 + Q], d = gd[t * 4 + Q];
#pragma unroll
                for (int j = 0; j < 4; ++j)
                    acc[t][4*Q+j] += bq[j] + bf16tof(a[j]) + bf16tof(d[j]);
            }

        // ---- 4. gather refill for next tile (consumes idx; E-refills unaffected) ----
        {
            const short* prs = tsrc + (size_t)nsi * DDIM;
            const short* prd = tdst + (size_t)ndi * DDIM;
#pragma unroll
            for (int t = 0; t < 4; ++t)
#pragma unroll
                for (int Q = 0; Q < 4; ++Q) {
                    const int c = 32 * t + 8 * Q + poff;
                    gs[t * 4 + Q] = *(const us4*)(prs + c);
                    gd[t * 4 + Q] = *(const us4*)(prd + c);
                }
        }
        __builtin_amdgcn_sched_barrier(0);         // pin gather refill above the compute tail

        // ---- 5. silu + pack ----
        unsigned hbf[4][4][2];
#pragma unroll
        for (int t = 0; t < 4; ++t)
#pragma unroll
            for (int Q = 0; Q < 4; ++Q) {
                float h0 = silu(acc[t][4*Q+0]), h1 = silu(acc[t][4*Q+1]);
                float h2 = silu(acc[t][4*Q+2]), h3 = silu(acc[t][4*Q+3]);
                hbf[t][Q][0] = pkbf(h0, h1);
                hbf[t][Q][1] = pkbf(h2, h3);
            }

        // ---- GEMM2 (straight, LDS weights) ----
        f32x16 acc2[4];
#pragma unroll
        for (int tt = 0; tt < 4; ++tt) {
            float bv = bol[32 * tt + lo];
#pragma unroll
            for (int r = 0; r < 16; ++r) acc2[tt][r] = bv;
        }

#pragma unroll
        for (int s = 0; s < 8; ++s) {
            const int t  = s >> 1;
            const int q0 = (2 * s) & 3;
            const int q1 = q0 + 1;
            unsigned X0 = hbf[t][q0][0], X1 = hbf[t][q0][1];
            unsigned Y0 = hbf[t][q1][0], Y1 = hbf[t][q1][1];
            plswap(X0, Y0);
            plswap(X1, Y1);
            u32x4 fv = { X0, X1, Y0, Y1 };        // A-frag: h[edge lo][16s+8hi + 0..7]
            bf16x8 hf = __builtin_bit_cast(bf16x8, fv);
            const short* wb = wlds + 16384 + s * 2048 + fslot;
#pragma unroll
            for (int tt = 0; tt < 4; ++tt) {
                bf16x8 w = *(const bf16x8*)(wb + tt * 512);
                acc2[tt] = __builtin_amdgcn_mfma_f32_32x32x16_bf16(hf, w, acc2[tt], 0, 0, 0);
            }
        }

        // ---- LayerNorm + coalesced NT store ----
        float gvw[4], bvw[4];
#pragma unroll
        for (int tt = 0; tt < 4; ++tt) {
            gvw[tt] = gl[32 * tt + lo];
            bvw[tt] = bl[32 * tt + lo];
        }

#pragma unroll
        for (int r = 0; r < 16; ++r) {
            float s1 = acc2[0][r] + acc2[1][r] + acc2[2][r] + acc2[3][r];
            float s2 = acc2[0][r]*acc2[0][r] + acc2[1][r]*acc2[1][r]
                     + acc2[2][r]*acc2[2][r] + acc2[3][r]*acc2[3][r];
#pragma unroll
            for (int msk = 1; msk < 32; msk <<= 1) {
                s1 += __shfl_xor(s1, msk, 64);
                s2 += __shfl_xor(s2, msk, 64);
            }
            const float mu   = s1 * (1.0f / 128.0f);
            const float var  = s2 * (1.0f / 128.0f) - mu * mu;
            const float rstd = rsqrtf(var + 1e-5f);
            const int   m    = (r & 3) + 8 * (r >> 2) + 4 * hi;
            const int   eo   = tb + m;
            if (eo < E) {
                float* po = out + (size_t)eo * DDIM;
#pragma unroll
                for (int tt = 0; tt < 4; ++tt) {
                    float o = (acc2[tt][r] - mu) * rstd * gvw[tt] + bvw[tt];
                    __builtin_nontemporal_store(o, po + 32 * tt + lo);
                }
            }
        }

        if (!hasnext) break;
        tb = nt;
    }
}

// ---- deep fallback (R4-verified): full-K kernel, no workspace tables ----
__global__ __launch_bounds__(256, 4) void edge_kernel_fullk(
    const float* __restrict__ efeat, const float* __restrict__ src_feat,
    const float* __restrict__ dst_feat, const int* __restrict__ src_idx,
    const int* __restrict__ dst_idx, const float* __restrict__ b0,
    const float* __restrict__ b_out, const float* __restrict__ ln_g,
    const float* __restrict__ ln_b, const short* __restrict__ w1frag,
    const short* __restrict__ w2frag, float* __restrict__ out, int E)
{
    const int tid  = threadIdx.x;
    const int wave = tid >> 6;
    const int lane = tid & 63;
    const int lo   = lane & 31;
    const int hi   = lane >> 5;
    const int ebase = blockIdx.x * 128 + wave * 32;

    const int erow = ebase + lo;
    const int ecl  = erow < E ? erow : E - 1;
    const int sidx = src_idx[ecl];
    const int didx = dst_idx[ecl];
    const float* pe = efeat    + (size_t)ecl  * DDIM;
    const float* ps = src_feat + (size_t)sidx * DDIM;
    const float* pd = dst_feat + (size_t)didx * DDIM;

    const int coff  = 8 * hi;
    const int poff  = 4 * hi;
    const int fslot = (lo * 2 + hi) * 8;

    float bov[4], gv[4], bv[4];
#pragma unroll
    for (int tt = 0; tt < 4; ++tt) {
        int n = 32 * tt + lo;
        bov[tt] = b_out[n]; gv[tt] = ln_g[n]; bv[tt] = ln_b[n];
    }

    f32x16 acc[4];
#pragma unroll
    for (int t = 0; t < 4; ++t)
#pragma unroll
        for (int Q = 0; Q < 4; ++Q) {
            f32x4 bq = *(const f32x4*)(b0 + 32 * t + 8 * Q + poff);
            acc[t][4*Q+0] = bq[0]; acc[t][4*Q+1] = bq[1];
            acc[t][4*Q+2] = bq[2]; acc[t][4*Q+3] = bq[3];
        }

#pragma unroll
    for (int seg = 0; seg < 3; ++seg) {
        const float* p = (seg == 0) ? pe : ((seg == 1) ? ps : pd);
#pragma unroll
        for (int ks = 0; ks < 8; ++ks) {
            const f32x4* pv = (const f32x4*)(p + 16 * ks + coff);
            f32x4 fa, fb;
            if (seg == 0) { fa = __builtin_nontemporal_load(pv); fb = __builtin_nontemporal_load(pv + 1); }
            else          { fa = pv[0];                          fb = pv[1]; }
            bf16x8 x = cvt8(fa, fb);
            const int s = seg * 8 + ks;
            const short* wb = w1frag + s * 2048 + fslot;
#pragma unroll
            for (int t = 0; t < 4; ++t) {
                bf16x8 w = *(const bf16x8*)(wb + t * 512);
                acc[t] = __builtin_amdgcn_mfma_f32_32x32x16_bf16(w, x, acc[t], 0, 0, 0);
            }
        }
    }

    unsigned hbf[4][4][2];
#pragma unroll
    for (int t = 0; t < 4; ++t)
#pragma unroll
        for (int Q = 0; Q < 4; ++Q) {
            float h0 = silu(acc[t][4*Q+0]), h1 = silu(acc[t][4*Q+1]);
            float h2 = silu(acc[t][4*Q+2]), h3 = silu(acc[t][4*Q+3]);
            hbf[t][Q][0] = pkbf(h0, h1);
            hbf[t][Q][1] = pkbf(h2, h3);
        }

    f32x16 acc2[4];
#pragma unroll
    for (int tt = 0; tt < 4; ++tt)
#pragma unroll
        for (int r = 0; r < 16; ++r) acc2[tt][r] = bov[tt];

#pragma unroll
    for (int s = 0; s < 8; ++s) {
        const int t  = s >> 1;
        const int q0 = (2 * s) & 3;
        const int q1 = q0 + 1;
        unsigned X0 = hbf[t][q0][0], X1 = hbf[t][q0][1];
        unsigned Y0 = hbf[t][q1][0], Y1 = hbf[t][q1][1];
        plswap(X0, Y0);
        plswap(X1, Y1);
        u32x4 fv = { X0, X1, Y0, Y1 };
        bf16x8 hf = __builtin_bit_cast(bf16x8, fv);
        const short* wb = w2frag + s * 2048 + fslot;
#pragma unroll
        for (int tt = 0; tt < 4; ++tt) {
            bf16x8 w = *(const bf16x8*)(wb + tt * 512);
            acc2[tt] = __builtin_amdgcn_mfma_f32_32x32x16_bf16(hf, w, acc2[tt], 0, 0, 0);
        }
    }

#pragma unroll
    for (int r = 0; r < 16; ++r) {
        float s1 = acc2[0][r] + acc2[1][r] + acc2[2][r] + acc2[3][r];
        float s2 = acc2[0][r]*acc2[0][r] + acc2[1][r]*acc2[1][r]
                 + acc2[2][r]*acc2[2][r] + acc2[3][r]*acc2[3][r];
#pragma unroll
        for (int msk = 1; msk < 32; msk <<= 1) {
            s1 += __shfl_xor(s1, msk, 64);
            s2 += __shfl_xor(s2, msk, 64);
        }
        const float mu   = s1 * (1.0f / 128.0f);
        const float var  = s2 * (1.0f / 128.0f) - mu * mu;
        const float rstd = rsqrtf(var + 1e-5f);
        const int   m    = (r & 3) + 8 * (r >> 2) + 4 * hi;
        const int   eo   = ebase + m;
        if (eo < E) {
            float* po = out + (size_t)eo * DDIM;
#pragma unroll
            for (int tt = 0; tt < 4; ++tt) {
                float o = (acc2[tt][r] - mu) * rstd * gv[tt] + bv[tt];
                __builtin_nontemporal_store(o, po + 32 * tt + lo);
            }
        }
    }
}

extern "C" void kernel_launch(void* const* d_in, const int* in_sizes, int n_in,
                              void* d_out, int out_size, void* d_ws, size_t ws_size,
                              hipStream_t stream)
{
    const float* efeat    = (const float*)d_in[0];
    const float* src_feat = (const float*)d_in[1];
    const float* dst_feat = (const float*)d_in[2];
    const int*   src_idx  = (const int*)d_in[3];
    const int*   dst_idx  = (const int*)d_in[4];
    const float* w_efeat  = (const float*)d_in[5];
    const float* w_src    = (const float*)d_in[6];
    const float* w_dst    = (const float*)d_in[7];
    const float* b0       = (const float*)d_in[8];
    const float* w_out    = (const float*)d_in[9];
    const float* b_out    = (const float*)d_in[10];
    const float* ln_g     = (const float*)d_in[11];
    const float* ln_b     = (const float*)d_in[12];
    float* out = (float*)d_out;
    const int E    = in_sizes[3];
    const int nsrc = in_sizes[1] / DDIM;
    const int ndst = in_sizes[2] / DDIM;

    short* w1frag = (short*)d_ws;                              // 96 KB
    short* w2frag = (short*)((char*)d_ws + 24 * 128 * 16 * 2); // 32 KB
    const size_t tab_off  = 128 * 1024;
    const size_t need_tab = tab_off + ((size_t)nsrc + (size_t)ndst) * DDIM * 2;

    prep_weights<<<256, 256, 0, stream>>>(w_efeat, w_src, w_dst, w_out, w1frag, w2frag);

    if (ws_size >= need_tab) {
        short* tsrc = (short*)((char*)d_ws + tab_off);
        short* tdst = tsrc + (size_t)nsrc * DDIM;
        node_table<<<(nsrc + 127) / 128, 256, 0, stream>>>(src_feat, w1frag, 8,  tsrc, nsrc);
        node_table<<<(ndst + 127) / 128, 256, 0, stream>>>(dst_feat, w1frag, 16, tdst, ndst);
        int nb = (E + 127) / 128;
        if (nb > 1024) nb = 1024;                 // persistent: ~2 blocks/CU resident
        edge_pipe<<<nb, 256, 0, stream>>>(efeat, tsrc, tdst, src_idx, dst_idx,
                                          b0, b_out, ln_g, ln_b, w1frag, w2frag, out, E);
    } else {
        const int nb = (E + 127) / 128;
        edge_kernel_fullk<<<nb, 256, 0, stream>>>(efeat, src_feat, dst_feat, src_idx, dst_idx,
                                                  b0, b_out, ln_g, ln_b, w1frag, w2frag, out, E);
    }
}

// Round 11
// 458.168 us; speedup vs baseline: 1.6181x; 1.5553x over previous
//
#include <hip/hip_runtime.h>
#include <hip/hip_bf16.h>

#define DDIM 128

typedef float    f32x16 __attribute__((ext_vector_type(16)));
typedef float    f32x4  __attribute__((ext_vector_type(4)));
typedef short    bf16x8 __attribute__((ext_vector_type(8)));
typedef __bf16   bf16x2t __attribute__((ext_vector_type(2)));
typedef unsigned u32x2  __attribute__((ext_vector_type(2)));
typedef unsigned u32x4  __attribute__((ext_vector_type(4)));
typedef unsigned short us4 __attribute__((ext_vector_type(4)));

__device__ __forceinline__ unsigned pkbf(float a, float b) {
    bf16x2t v; v[0] = (__bf16)a; v[1] = (__bf16)b;
    return __builtin_bit_cast(unsigned, v);
}

__device__ __forceinline__ short f2bf16s(float a) {
    __bf16 b = (__bf16)a;
    return __builtin_bit_cast(short, b);
}

__device__ __forceinline__ float bf16tof(unsigned short u) {
    return __builtin_bit_cast(float, ((unsigned)u) << 16);
}

__device__ __forceinline__ bf16x8 cvt8(f32x4 a, f32x4 b) {
    u32x4 u = { pkbf(a[0],a[1]), pkbf(a[2],a[3]), pkbf(b[0],b[1]), pkbf(b[2],b[3]) };
    return __builtin_bit_cast(bf16x8, u);
}

__device__ __forceinline__ void plswap(unsigned &x, unsigned &y) {
    u32x2 r = __builtin_amdgcn_permlane32_swap(x, y, false, false);
    x = r[0]; y = r[1];
}

__device__ __forceinline__ float silu(float x) {
    return x * __builtin_amdgcn_rcpf(1.0f + __expf(-x));
}

// ---- kernel 0: FRAGMENT-MAJOR bf16 weights (layout verified R2-R10).
__global__ void prep_weights(const float* __restrict__ we, const float* __restrict__ wsrc,
                             const float* __restrict__ wdst, const float* __restrict__ wout,
                             short* __restrict__ w1frag, short* __restrict__ w2frag) {
    int tid = blockIdx.x * 256 + threadIdx.x;        // 65536 total
    if (tid < 24 * 128 * 16) {
        int k8 = tid & 7;
        int hi = (tid >> 3) & 1;
        int n  = (tid >> 4) & 127;
        int s  = tid >> 11;
        int col = 16 * s + 8 * hi + k8;              // 0..383
        const float* src = (col < 128) ? we : ((col < 256) ? wsrc : wdst);
        w1frag[tid] = f2bf16s(src[n * 128 + (col & 127)]);
    } else {
        int t2 = tid - 24 * 128 * 16;
        int k8 = t2 & 7;
        int hi = (t2 >> 3) & 1;
        int n  = (t2 >> 4) & 127;
        int s  = t2 >> 11;
        int col = 16 * s + 8 * hi + k8;              // 0..127
        w2frag[t2] = f2bf16s(wout[n * 128 + col]);
    }
}

// ---- node-table kernel (verified R5-R10): tbl[row] = feat[row] @ Wseg^T (bf16, no bias).
__global__ __launch_bounds__(256, 4) void node_table(
    const float* __restrict__ feat, const short* __restrict__ w1frag,
    int segoff, short* __restrict__ tbl, int N)
{
    const int tid  = threadIdx.x;
    const int wave = tid >> 6;
    const int lane = tid & 63;
    const int lo   = lane & 31;
    const int hi   = lane >> 5;
    const int base = blockIdx.x * 128 + wave * 32;
    const int row  = base + lo;
    const int rcl  = row < N ? row : N - 1;
    const float* pn = feat + (size_t)rcl * DDIM;
    const int coff  = 8 * hi;
    const int fslot = (lo * 2 + hi) * 8;

    f32x16 acc[4];
#pragma unroll
    for (int t = 0; t < 4; ++t)
#pragma unroll
        for (int r = 0; r < 16; ++r) acc[t][r] = 0.0f;

#pragma unroll
    for (int s = 0; s < 8; ++s) {
        const f32x4* pv = (const f32x4*)(pn + 16 * s + coff);
        f32x4 fa = pv[0], fb = pv[1];
        bf16x8 a = cvt8(fa, fb);
        const short* wb = w1frag + (segoff + s) * 2048 + fslot;
#pragma unroll
        for (int t = 0; t < 4; ++t) {
            bf16x8 w = *(const bf16x8*)(wb + t * 512);
            acc[t] = __builtin_amdgcn_mfma_f32_32x32x16_bf16(a, w, acc[t], 0, 0, 0);
        }
    }

#pragma unroll
    for (int r = 0; r < 16; ++r) {
        const int m = (r & 3) + 8 * (r >> 2) + 4 * hi;
        const int node = base + m;
        if (node < N) {
            short* po = tbl + (size_t)node * DDIM;
#pragma unroll
            for (int t = 0; t < 4; ++t)
                po[32 * t + lo] = f2bf16s(acc[t][r]);
        }
    }
}

// ---- R11: R7 edge kernel, ALL nontemporal hints removed (A/B vs R7).
__global__ __launch_bounds__(256, 2) void edge_kernel_tab(
    const float* __restrict__ efeat, const short* __restrict__ tsrc,
    const short* __restrict__ tdst, const int* __restrict__ src_idx,
    const int* __restrict__ dst_idx, const float* __restrict__ b0,
    const float* __restrict__ b_out, const float* __restrict__ ln_g,
    const float* __restrict__ ln_b, const short* __restrict__ w1frag,
    const short* __restrict__ w2frag, float* __restrict__ out, int E)
{
    const int tid  = threadIdx.x;
    const int wave = tid >> 6;
    const int lane = tid & 63;
    const int lo   = lane & 31;
    const int hi   = lane >> 5;
    const int ebase = blockIdx.x * 128 + wave * 32;

    const int erow = ebase + lo;              // this lane's edge
    const int ecl  = erow < E ? erow : E - 1;
    const int sidx = src_idx[ecl];
    const int didx = dst_idx[ecl];
    const float* pe = efeat + (size_t)ecl * DDIM;
    const short* prs = tsrc + (size_t)sidx * DDIM;
    const short* prd = tdst + (size_t)didx * DDIM;

    const int coff  = 8 * hi;                 // k sub-offset within a 16-wide K step
    const int poff  = 4 * hi;                 // col sub-offset in transposed D-layout
    const int fslot = (lo * 2 + hi) * 8;      // weight fragment slot (shorts)

    // ---- efeat burst: all 16 loads issued first (plain cached loads) ----
    f32x4 fa[8], fb[8];
#pragma unroll
    for (int s = 0; s < 8; ++s) {
        const f32x4* pv = (const f32x4*)(pe + 16 * s + coff);
        fa[s] = pv[0];
        fb[s] = pv[1];
    }

    // ---- gather burst (newer; consumed after GEMM1) ----
    us4 tsv[16], tdv[16];
#pragma unroll
    for (int t = 0; t < 4; ++t)
#pragma unroll
        for (int Q = 0; Q < 4; ++Q) {
            const int c = 32 * t + 8 * Q + poff;
            tsv[t * 4 + Q] = *(const us4*)(prs + c);
            tdv[t * 4 + Q] = *(const us4*)(prd + c);
        }

    // ---- GEMM1 (transposed): acc[t] rows = n, cols = edges; init b0 ----
    f32x16 acc[4];
#pragma unroll
    for (int t = 0; t < 4; ++t)
#pragma unroll
        for (int Q = 0; Q < 4; ++Q) {
            f32x4 bq = *(const f32x4*)(b0 + 32 * t + 8 * Q + poff);
            acc[t][4*Q+0] = bq[0]; acc[t][4*Q+1] = bq[1];
            acc[t][4*Q+2] = bq[2]; acc[t][4*Q+3] = bq[3];
        }

#pragma unroll
    for (int s = 0; s < 8; ++s) {
        bf16x8 x = cvt8(fa[s], fb[s]);               // B-frag: efeat[edge lo][16s+8hi+j]
        const short* wb = w1frag + s * 2048 + fslot; // A-frag: W_e[32t+lo][16s+8hi+j]
#pragma unroll
        for (int t = 0; t < 4; ++t) {
            bf16x8 w = *(const bf16x8*)(wb + t * 512);
            acc[t] = __builtin_amdgcn_mfma_f32_32x32x16_bf16(w, x, acc[t], 0, 0, 0);
        }
    }

    // ---- add gathered table rows (lane-local; c = 32t+8Q+4hi+j) ----
#pragma unroll
    for (int t = 0; t < 4; ++t)
#pragma unroll
        for (int Q = 0; Q < 4; ++Q) {
            us4 a = tsv[t * 4 + Q], d = tdv[t * 4 + Q];
#pragma unroll
            for (int j = 0; j < 4; ++j)
                acc[t][4*Q+j] += bf16tof(a[j]) + bf16tof(d[j]);
        }

    // ---- SiLU + pack to bf16, lane-local ----
    unsigned hbf[4][4][2];
#pragma unroll
    for (int t = 0; t < 4; ++t)
#pragma unroll
        for (int Q = 0; Q < 4; ++Q) {
            float h0 = silu(acc[t][4*Q+0]), h1 = silu(acc[t][4*Q+1]);
            float h2 = silu(acc[t][4*Q+2]), h3 = silu(acc[t][4*Q+3]);
            hbf[t][Q][0] = pkbf(h0, h1);
            hbf[t][Q][1] = pkbf(h2, h3);
        }

    // ---- GEMM2 (straight): y = silu(h) @ W2^T ----
    float bov[4];
#pragma unroll
    for (int tt = 0; tt < 4; ++tt) bov[tt] = b_out[32 * tt + lo];

    f32x16 acc2[4];
#pragma unroll
    for (int tt = 0; tt < 4; ++tt)
#pragma unroll
        for (int r = 0; r < 16; ++r) acc2[tt][r] = bov[tt];

#pragma unroll
    for (int s = 0; s < 8; ++s) {
        const int t  = s >> 1;
        const int q0 = (2 * s) & 3;
        const int q1 = q0 + 1;
        unsigned X0 = hbf[t][q0][0], X1 = hbf[t][q0][1];
        unsigned Y0 = hbf[t][q1][0], Y1 = hbf[t][q1][1];
        plswap(X0, Y0);
        plswap(X1, Y1);
        u32x4 fv = { X0, X1, Y0, Y1 };       // A-frag: h[edge lo][16s+8hi + 0..7]
        bf16x8 hf = __builtin_bit_cast(bf16x8, fv);
        const short* wb = w2frag + s * 2048 + fslot;
#pragma unroll
        for (int tt = 0; tt < 4; ++tt) {
            bf16x8 w = *(const bf16x8*)(wb + tt * 512);
            acc2[tt] = __builtin_amdgcn_mfma_f32_32x32x16_bf16(hf, w, acc2[tt], 0, 0, 0);
        }
    }

    // ---- LayerNorm (butterfly over 32 lanes) + coalesced store (plain) ----
    float gv[4], bv[4];
#pragma unroll
    for (int tt = 0; tt < 4; ++tt) {
        gv[tt] = ln_g[32 * tt + lo];
        bv[tt] = ln_b[32 * tt + lo];
    }

#pragma unroll
    for (int r = 0; r < 16; ++r) {
        float s1 = acc2[0][r] + acc2[1][r] + acc2[2][r] + acc2[3][r];
        float s2 = acc2[0][r]*acc2[0][r] + acc2[1][r]*acc2[1][r]
                 + acc2[2][r]*acc2[2][r] + acc2[3][r]*acc2[3][r];
#pragma unroll
        for (int msk = 1; msk < 32; msk <<= 1) {
            s1 += __shfl_xor(s1, msk, 64);
            s2 += __shfl_xor(s2, msk, 64);
        }
        const float mu   = s1 * (1.0f / 128.0f);
        const float var  = s2 * (1.0f / 128.0f) - mu * mu;
        const float rstd = rsqrtf(var + 1e-5f);
        const int   m    = (r & 3) + 8 * (r >> 2) + 4 * hi;
        const int   eo   = ebase + m;
        if (eo < E) {
            float* po = out + (size_t)eo * DDIM;
#pragma unroll
            for (int tt = 0; tt < 4; ++tt) {
                float o = (acc2[tt][r] - mu) * rstd * gv[tt] + bv[tt];
                po[32 * tt + lo] = o;
            }
        }
    }
}

// ---- deep fallback (R4-verified): full-K kernel, no workspace tables ----
__global__ __launch_bounds__(256, 4) void edge_kernel_fullk(
    const float* __restrict__ efeat, const float* __restrict__ src_feat,
    const float* __restrict__ dst_feat, const int* __restrict__ src_idx,
    const int* __restrict__ dst_idx, const float* __restrict__ b0,
    const float* __restrict__ b_out, const float* __restrict__ ln_g,
    const float* __restrict__ ln_b, const short* __restrict__ w1frag,
    const short* __restrict__ w2frag, float* __restrict__ out, int E)
{
    const int tid  = threadIdx.x;
    const int wave = tid >> 6;
    const int lane = tid & 63;
    const int lo   = lane & 31;
    const int hi   = lane >> 5;
    const int ebase = blockIdx.x * 128 + wave * 32;

    const int erow = ebase + lo;
    const int ecl  = erow < E ? erow : E - 1;
    const int sidx = src_idx[ecl];
    const int didx = dst_idx[ecl];
    const float* pe = efeat    + (size_t)ecl  * DDIM;
    const float* ps = src_feat + (size_t)sidx * DDIM;
    const float* pd = dst_feat + (size_t)didx * DDIM;

    const int coff  = 8 * hi;
    const int poff  = 4 * hi;
    const int fslot = (lo * 2 + hi) * 8;

    float bov[4], gv[4], bv[4];
#pragma unroll
    for (int tt = 0; tt < 4; ++tt) {
        int n = 32 * tt + lo;
        bov[tt] = b_out[n]; gv[tt] = ln_g[n]; bv[tt] = ln_b[n];
    }

    f32x16 acc[4];
#pragma unroll
    for (int t = 0; t < 4; ++t)
#pragma unroll
        for (int Q = 0; Q < 4; ++Q) {
            f32x4 bq = *(const f32x4*)(b0 + 32 * t + 8 * Q + poff);
            acc[t][4*Q+0] = bq[0]; acc[t][4*Q+1] = bq[1];
            acc[t][4*Q+2] = bq[2]; acc[t][4*Q+3] = bq[3];
        }

#pragma unroll
    for (int seg = 0; seg < 3; ++seg) {
        const float* p = (seg == 0) ? pe : ((seg == 1) ? ps : pd);
#pragma unroll
        for (int ks = 0; ks < 8; ++ks) {
            const f32x4* pv = (const f32x4*)(p + 16 * ks + coff);
            f32x4 fa = pv[0], fb = pv[1];
            bf16x8 x = cvt8(fa, fb);
            const int s = seg * 8 + ks;
            const short* wb = w1frag + s * 2048 + fslot;
#pragma unroll
            for (int t = 0; t < 4; ++t) {
                bf16x8 w = *(const bf16x8*)(wb + t * 512);
                acc[t] = __builtin_amdgcn_mfma_f32_32x32x16_bf16(w, x, acc[t], 0, 0, 0);
            }
        }
    }

    unsigned hbf[4][4][2];
#pragma unroll
    for (int t = 0; t < 4; ++t)
#pragma unroll
        for (int Q = 0; Q < 4; ++Q) {
            float h0 = silu(acc[t][4*Q+0]), h1 = silu(acc[t][4*Q+1]);
            float h2 = silu(acc[t][4*Q+2]), h3 = silu(acc[t][4*Q+3]);
            hbf[t][Q][0] = pkbf(h0, h1);
            hbf[t][Q][1] = pkbf(h2, h3);
        }

    f32x16 acc2[4];
#pragma unroll
    for (int tt = 0; tt < 4; ++tt)
#pragma unroll
        for (int r = 0; r < 16; ++r) acc2[tt][r] = bov[tt];

#pragma unroll
    for (int s = 0; s < 8; ++s) {
        const int t  = s >> 1;
        const int q0 = (2 * s) & 3;
        const int q1 = q0 + 1;
        unsigned X0 = hbf[t][q0][0], X1 = hbf[t][q0][1];
        unsigned Y0 = hbf[t][q1][0], Y1 = hbf[t][q1][1];
        plswap(X0, Y0);
        plswap(X1, Y1);
        u32x4 fv = { X0, X1, Y0, Y1 };
        bf16x8 hf = __builtin_bit_cast(bf16x8, fv);
        const short* wb = w2frag + s * 2048 + fslot;
#pragma unroll
        for (int tt = 0; tt < 4; ++tt) {
            bf16x8 w = *(const bf16x8*)(wb + tt * 512);
            acc2[tt] = __builtin_amdgcn_mfma_f32_32x32x16_bf16(hf, w, acc2[tt], 0, 0, 0);
        }
    }

#pragma unroll
    for (int r = 0; r < 16; ++r) {
        float s1 = acc2[0][r] + acc2[1][r] + acc2[2][r] + acc2[3][r];
        float s2 = acc2[0][r]*acc2[0][r] + acc2[1][r]*acc2[1][r]
                 + acc2[2][r]*acc2[2][r] + acc2[3][r]*acc2[3][r];
#pragma unroll
        for (int msk = 1; msk < 32; msk <<= 1) {
            s1 += __shfl_xor(s1, msk, 64);
            s2 += __shfl_xor(s2, msk, 64);
        }
        const float mu   = s1 * (1.0f / 128.0f);
        const float var  = s2 * (1.0f / 128.0f) - mu * mu;
        const float rstd = rsqrtf(var + 1e-5f);
        const int   m    = (r & 3) + 8 * (r >> 2) + 4 * hi;
        const int   eo   = ebase + m;
        if (eo < E) {
            float* po = out + (size_t)eo * DDIM;
#pragma unroll
            for (int tt = 0; tt < 4; ++tt) {
                float o = (acc2[tt][r] - mu) * rstd * gv[tt] + bv[tt];
                po[32 * tt + lo] = o;
            }
        }
    }
}

extern "C" void kernel_launch(void* const* d_in, const int* in_sizes, int n_in,
                              void* d_out, int out_size, void* d_ws, size_t ws_size,
                              hipStream_t stream)
{
    const float* efeat    = (const float*)d_in[0];
    const float* src_feat = (const float*)d_in[1];
    const float* dst_feat = (const float*)d_in[2];
    const int*   src_idx  = (const int*)d_in[3];
    const int*   dst_idx  = (const int*)d_in[4];
    const float* w_efeat  = (const float*)d_in[5];
    const float* w_src    = (const float*)d_in[6];
    const float* w_dst    = (const float*)d_in[7];
    const float* b0       = (const float*)d_in[8];
    const float* w_out    = (const float*)d_in[9];
    const float* b_out    = (const float*)d_in[10];
    const float* ln_g     = (const float*)d_in[11];
    const float* ln_b     = (const float*)d_in[12];
    float* out = (float*)d_out;
    const int E    = in_sizes[3];
    const int nsrc = in_sizes[1] / DDIM;
    const int ndst = in_sizes[2] / DDIM;

    short* w1frag = (short*)d_ws;                              // 96 KB
    short* w2frag = (short*)((char*)d_ws + 24 * 128 * 16 * 2); // 32 KB
    const size_t tab_off  = 128 * 1024;
    const size_t need_tab = tab_off + ((size_t)nsrc + (size_t)ndst) * DDIM * 2;

    prep_weights<<<256, 256, 0, stream>>>(w_efeat, w_src, w_dst, w_out, w1frag, w2frag);

    const int nb = (E + 127) / 128;
    if (ws_size >= need_tab) {
        short* tsrc = (short*)((char*)d_ws + tab_off);
        short* tdst = tsrc + (size_t)nsrc * DDIM;
        node_table<<<(nsrc + 127) / 128, 256, 0, stream>>>(src_feat, w1frag, 8,  tsrc, nsrc);
        node_table<<<(ndst + 127) / 128, 256, 0, stream>>>(dst_feat, w1frag, 16, tdst, ndst);
        edge_kernel_tab<<<nb, 256, 0, stream>>>(efeat, tsrc, tdst, src_idx, dst_idx,
                                                b0, b_out, ln_g, ln_b, w1frag, w2frag, out, E);
    } else {
        edge_kernel_fullk<<<nb, 256, 0, stream>>>(efeat, src_feat, dst_feat, src_idx, dst_idx,
                                                  b0, b_out, ln_g, ln_b, w1frag, w2frag, out, E);
    }
}

// Round 12
// 411.182 us; speedup vs baseline: 1.8030x; 1.1143x over previous
//
#include <hip/hip_runtime.h>
#include <hip/hip_bf16.h>

#define DDIM 128

typedef float    f32x16 __attribute__((ext_vector_type(16)));
typedef float    f32x4  __attribute__((ext_vector_type(4)));
typedef short    bf16x8 __attribute__((ext_vector_type(8)));
typedef __bf16   bf16x2t __attribute__((ext_vector_type(2)));
typedef unsigned u32x2  __attribute__((ext_vector_type(2)));
typedef unsigned u32x4  __attribute__((ext_vector_type(4)));
typedef unsigned short us4 __attribute__((ext_vector_type(4)));
typedef unsigned short us8 __attribute__((ext_vector_type(8)));

__device__ __forceinline__ unsigned pkbf(float a, float b) {
    bf16x2t v; v[0] = (__bf16)a; v[1] = (__bf16)b;
    return __builtin_bit_cast(unsigned, v);
}

__device__ __forceinline__ short f2bf16s(float a) {
    __bf16 b = (__bf16)a;
    return __builtin_bit_cast(short, b);
}

__device__ __forceinline__ float bf16tof(unsigned short u) {
    return __builtin_bit_cast(float, ((unsigned)u) << 16);
}

__device__ __forceinline__ bf16x8 cvt8(f32x4 a, f32x4 b) {
    u32x4 u = { pkbf(a[0],a[1]), pkbf(a[2],a[3]), pkbf(b[0],b[1]), pkbf(b[2],b[3]) };
    return __builtin_bit_cast(bf16x8, u);
}

__device__ __forceinline__ void plswap(unsigned &x, unsigned &y) {
    u32x2 r = __builtin_amdgcn_permlane32_swap(x, y, false, false);
    x = r[0]; y = r[1];
}

__device__ __forceinline__ float silu(float x) {
    return x * __builtin_amdgcn_rcpf(1.0f + __expf(-x));
}

// ---- kernel 0: FRAGMENT-MAJOR bf16 weights (layout verified R2-R11).
__global__ void prep_weights(const float* __restrict__ we, const float* __restrict__ wsrc,
                             const float* __restrict__ wdst, const float* __restrict__ wout,
                             short* __restrict__ w1frag, short* __restrict__ w2frag) {
    int tid = blockIdx.x * 256 + threadIdx.x;        // 65536 total
    if (tid < 24 * 128 * 16) {
        int k8 = tid & 7;
        int hi = (tid >> 3) & 1;
        int n  = (tid >> 4) & 127;
        int s  = tid >> 11;
        int col = 16 * s + 8 * hi + k8;              // 0..383
        const float* src = (col < 128) ? we : ((col < 256) ? wsrc : wdst);
        w1frag[tid] = f2bf16s(src[n * 128 + (col & 127)]);
    } else {
        int t2 = tid - 24 * 128 * 16;
        int k8 = t2 & 7;
        int hi = (t2 >> 3) & 1;
        int n  = (t2 >> 4) & 127;
        int s  = t2 >> 11;
        int col = 16 * s + 8 * hi + k8;              // 0..127
        w2frag[t2] = f2bf16s(wout[n * 128 + col]);
    }
}

// ---- node-table kernel, R12: weight slice staged in LDS (vmcnt queue = feat only).
__global__ __launch_bounds__(256, 4) void node_table(
    const float* __restrict__ feat, const short* __restrict__ w1frag,
    int segoff, short* __restrict__ tbl, int N)
{
    __shared__ __align__(16) short wl[16384];        // 32 KB: this segment's 8 K-steps

    const int tid  = threadIdx.x;
    {
        const us8* s1 = (const us8*)(w1frag + segoff * 2048);
        us8* d1 = (us8*)wl;
        for (int i = tid; i < 2048; i += 256) d1[i] = s1[i];
    }
    __syncthreads();

    const int wave = tid >> 6;
    const int lane = tid & 63;
    const int lo   = lane & 31;
    const int hi   = lane >> 5;
    const int base = blockIdx.x * 128 + wave * 32;
    const int row  = base + lo;
    const int rcl  = row < N ? row : N - 1;
    const float* pn = feat + (size_t)rcl * DDIM;
    const int coff  = 8 * hi;
    const int fslot = (lo * 2 + hi) * 8;

    // efeat burst first -> oldest in queue, consumed in order
    f32x4 fa[8], fb[8];
#pragma unroll
    for (int s = 0; s < 8; ++s) {
        const f32x4* pv = (const f32x4*)(pn + 16 * s + coff);
        fa[s] = pv[0];
        fb[s] = pv[1];
    }

    f32x16 acc[4];
#pragma unroll
    for (int t = 0; t < 4; ++t)
#pragma unroll
        for (int r = 0; r < 16; ++r) acc[t][r] = 0.0f;

#pragma unroll
    for (int s = 0; s < 8; ++s) {
        bf16x8 a = cvt8(fa[s], fb[s]);
        const short* wb = wl + s * 2048 + fslot;
#pragma unroll
        for (int t = 0; t < 4; ++t) {
            bf16x8 w = *(const bf16x8*)(wb + t * 512);
            acc[t] = __builtin_amdgcn_mfma_f32_32x32x16_bf16(a, w, acc[t], 0, 0, 0);
        }
    }

#pragma unroll
    for (int r = 0; r < 16; ++r) {
        const int m = (r & 3) + 8 * (r >> 2) + 4 * hi;
        const int node = base + m;
        if (node < N) {
            short* po = tbl + (size_t)node * DDIM;
#pragma unroll
            for (int t = 0; t < 4; ++t)
                po[32 * t + lo] = f2bf16s(acc[t][r]);
        }
    }
}

// ---- R12 edge kernel: R11 structure + ALL weights/params in LDS.
// vmcnt queue holds ONLY efeat burst + gather burst (oldest-first consumption):
// first MFMA waits just for fa[0]; gathers retire under GEMM1's compute.
__global__ __launch_bounds__(256, 2) void edge_kernel_tab(
    const float* __restrict__ efeat, const short* __restrict__ tsrc,
    const short* __restrict__ tdst, const int* __restrict__ src_idx,
    const int* __restrict__ dst_idx, const float* __restrict__ b0,
    const float* __restrict__ b_out, const float* __restrict__ ln_g,
    const float* __restrict__ ln_b, const short* __restrict__ w1frag,
    const short* __restrict__ w2frag, float* __restrict__ out, int E)
{
    __shared__ __align__(16) short wlds[32768];      // [0,16K): W_e frags  [16K,32K): W2 frags
    __shared__ __align__(16) float b0l[128], bol[128], gl[128], bl[128];

    const int tid = threadIdx.x;
    {
        const us8* s1 = (const us8*)w1frag;          // first 32 KB of w1frag = W_e slice (s=0..7)
        us8* d1 = (us8*)wlds;
        for (int i = tid; i < 2048; i += 256) d1[i] = s1[i];
        const us8* s2 = (const us8*)w2frag;
        us8* d2 = (us8*)(wlds + 16384);
        for (int i = tid; i < 2048; i += 256) d2[i] = s2[i];
        if (tid < 128) {
            b0l[tid] = b0[tid];   bol[tid] = b_out[tid];
            gl[tid]  = ln_g[tid]; bl[tid]  = ln_b[tid];
        }
    }
    __syncthreads();

    const int wave = tid >> 6;
    const int lane = tid & 63;
    const int lo   = lane & 31;
    const int hi   = lane >> 5;
    const int ebase = blockIdx.x * 128 + wave * 32;

    const int erow = ebase + lo;              // this lane's edge
    const int ecl  = erow < E ? erow : E - 1;
    const int sidx = src_idx[ecl];
    const int didx = dst_idx[ecl];
    const float* pe = efeat + (size_t)ecl * DDIM;
    const short* prs = tsrc + (size_t)sidx * DDIM;
    const short* prd = tdst + (size_t)didx * DDIM;

    const int coff  = 8 * hi;                 // k sub-offset within a 16-wide K step
    const int poff  = 4 * hi;                 // col sub-offset in transposed D-layout
    const int fslot = (lo * 2 + hi) * 8;      // weight fragment slot (shorts)

    // ---- efeat burst: 16 loads, OLDEST in the vmcnt queue ----
    f32x4 fa[8], fb[8];
#pragma unroll
    for (int s = 0; s < 8; ++s) {
        const f32x4* pv = (const f32x4*)(pe + 16 * s + coff);
        fa[s] = pv[0];
        fb[s] = pv[1];
    }

    // ---- gather burst (younger; consumed after GEMM1) ----
    us4 tsv[16], tdv[16];
#pragma unroll
    for (int t = 0; t < 4; ++t)
#pragma unroll
        for (int Q = 0; Q < 4; ++Q) {
            const int c = 32 * t + 8 * Q + poff;
            tsv[t * 4 + Q] = *(const us4*)(prs + c);
            tdv[t * 4 + Q] = *(const us4*)(prd + c);
        }

    // ---- GEMM1 (transposed): acc init from LDS b0 (no vmcnt) ----
    f32x16 acc[4];
#pragma unroll
    for (int t = 0; t < 4; ++t)
#pragma unroll
        for (int Q = 0; Q < 4; ++Q) {
            f32x4 bq = *(const f32x4*)(b0l + 32 * t + 8 * Q + poff);
            acc[t][4*Q+0] = bq[0]; acc[t][4*Q+1] = bq[1];
            acc[t][4*Q+2] = bq[2]; acc[t][4*Q+3] = bq[3];
        }

#pragma unroll
    for (int s = 0; s < 8; ++s) {
        bf16x8 x = cvt8(fa[s], fb[s]);               // B-frag: efeat[edge lo][16s+8hi+j]
        const short* wb = wlds + s * 2048 + fslot;   // A-frag from LDS (lgkmcnt only)
#pragma unroll
        for (int t = 0; t < 4; ++t) {
            bf16x8 w = *(const bf16x8*)(wb + t * 512);
            acc[t] = __builtin_amdgcn_mfma_f32_32x32x16_bf16(w, x, acc[t], 0, 0, 0);
        }
    }

    // ---- add gathered table rows (lane-local; c = 32t+8Q+4hi+j) ----
#pragma unroll
    for (int t = 0; t < 4; ++t)
#pragma unroll
        for (int Q = 0; Q < 4; ++Q) {
            us4 a = tsv[t * 4 + Q], d = tdv[t * 4 + Q];
#pragma unroll
            for (int j = 0; j < 4; ++j)
                acc[t][4*Q+j] += bf16tof(a[j]) + bf16tof(d[j]);
        }

    // ---- SiLU + pack to bf16, lane-local ----
    unsigned hbf[4][4][2];
#pragma unroll
    for (int t = 0; t < 4; ++t)
#pragma unroll
        for (int Q = 0; Q < 4; ++Q) {
            float h0 = silu(acc[t][4*Q+0]), h1 = silu(acc[t][4*Q+1]);
            float h2 = silu(acc[t][4*Q+2]), h3 = silu(acc[t][4*Q+3]);
            hbf[t][Q][0] = pkbf(h0, h1);
            hbf[t][Q][1] = pkbf(h2, h3);
        }

    // ---- GEMM2 (straight): weights from LDS ----
    f32x16 acc2[4];
#pragma unroll
    for (int tt = 0; tt < 4; ++tt) {
        float bv = bol[32 * tt + lo];
#pragma unroll
        for (int r = 0; r < 16; ++r) acc2[tt][r] = bv;
    }

#pragma unroll
    for (int s = 0; s < 8; ++s) {
        const int t  = s >> 1;
        const int q0 = (2 * s) & 3;
        const int q1 = q0 + 1;
        unsigned X0 = hbf[t][q0][0], X1 = hbf[t][q0][1];
        unsigned Y0 = hbf[t][q1][0], Y1 = hbf[t][q1][1];
        plswap(X0, Y0);
        plswap(X1, Y1);
        u32x4 fv = { X0, X1, Y0, Y1 };       // A-frag: h[edge lo][16s+8hi + 0..7]
        bf16x8 hf = __builtin_bit_cast(bf16x8, fv);
        const short* wb = wlds + 16384 + s * 2048 + fslot;
#pragma unroll
        for (int tt = 0; tt < 4; ++tt) {
            bf16x8 w = *(const bf16x8*)(wb + tt * 512);
            acc2[tt] = __builtin_amdgcn_mfma_f32_32x32x16_bf16(hf, w, acc2[tt], 0, 0, 0);
        }
    }

    // ---- LayerNorm (butterfly over 32 lanes) + coalesced store ----
    float gvw[4], bvw[4];
#pragma unroll
    for (int tt = 0; tt < 4; ++tt) {
        gvw[tt] = gl[32 * tt + lo];
        bvw[tt] = bl[32 * tt + lo];
    }

#pragma unroll
    for (int r = 0; r < 16; ++r) {
        float s1 = acc2[0][r] + acc2[1][r] + acc2[2][r] + acc2[3][r];
        float s2 = acc2[0][r]*acc2[0][r] + acc2[1][r]*acc2[1][r]
                 + acc2[2][r]*acc2[2][r] + acc2[3][r]*acc2[3][r];
#pragma unroll
        for (int msk = 1; msk < 32; msk <<= 1) {
            s1 += __shfl_xor(s1, msk, 64);
            s2 += __shfl_xor(s2, msk, 64);
        }
        const float mu   = s1 * (1.0f / 128.0f);
        const float var  = s2 * (1.0f / 128.0f) - mu * mu;
        const float rstd = rsqrtf(var + 1e-5f);
        const int   m    = (r & 3) + 8 * (r >> 2) + 4 * hi;
        const int   eo   = ebase + m;
        if (eo < E) {
            float* po = out + (size_t)eo * DDIM;
#pragma unroll
            for (int tt = 0; tt < 4; ++tt) {
                float o = (acc2[tt][r] - mu) * rstd * gvw[tt] + bvw[tt];
                po[32 * tt + lo] = o;
            }
        }
    }
}

// ---- deep fallback (R4-verified): full-K kernel, no workspace tables ----
__global__ __launch_bounds__(256, 4) void edge_kernel_fullk(
    const float* __restrict__ efeat, const float* __restrict__ src_feat,
    const float* __restrict__ dst_feat, const int* __restrict__ src_idx,
    const int* __restrict__ dst_idx, const float* __restrict__ b0,
    const float* __restrict__ b_out, const float* __restrict__ ln_g,
    const float* __restrict__ ln_b, const short* __restrict__ w1frag,
    const short* __restrict__ w2frag, float* __restrict__ out, int E)
{
    const int tid  = threadIdx.x;
    const int wave = tid >> 6;
    const int lane = tid & 63;
    const int lo   = lane & 31;
    const int hi   = lane >> 5;
    const int ebase = blockIdx.x * 128 + wave * 32;

    const int erow = ebase + lo;
    const int ecl  = erow < E ? erow : E - 1;
    const int sidx = src_idx[ecl];
    const int didx = dst_idx[ecl];
    const float* pe = efeat    + (size_t)ecl  * DDIM;
    const float* ps = src_feat + (size_t)sidx * DDIM;
    const float* pd = dst_feat + (size_t)didx * DDIM;

    const int coff  = 8 * hi;
    const int poff  = 4 * hi;
    const int fslot = (lo * 2 + hi) * 8;

    float bov[4], gv[4], bv[4];
#pragma unroll
    for (int tt = 0; tt < 4; ++tt) {
        int n = 32 * tt + lo;
        bov[tt] = b_out[n]; gv[tt] = ln_g[n]; bv[tt] = ln_b[n];
    }

    f32x16 acc[4];
#pragma unroll
    for (int t = 0; t < 4; ++t)
#pragma unroll
        for (int Q = 0; Q < 4; ++Q) {
            f32x4 bq = *(const f32x4*)(b0 + 32 * t + 8 * Q + poff);
            acc[t][4*Q+0] = bq[0]; acc[t][4*Q+1] = bq[1];
            acc[t][4*Q+2] = bq[2]; acc[t][4*Q+3] = bq[3];
        }

#pragma unroll
    for (int seg = 0; seg < 3; ++seg) {
        const float* p = (seg == 0) ? pe : ((seg == 1) ? ps : pd);
#pragma unroll
        for (int ks = 0; ks < 8; ++ks) {
            const f32x4* pv = (const f32x4*)(p + 16 * ks + coff);
            f32x4 fa = pv[0], fb = pv[1];
            bf16x8 x = cvt8(fa, fb);
            const int s = seg * 8 + ks;
            const short* wb = w1frag + s * 2048 + fslot;
#pragma unroll
            for (int t = 0; t < 4; ++t) {
                bf16x8 w = *(const bf16x8*)(wb + t * 512);
                acc[t] = __builtin_amdgcn_mfma_f32_32x32x16_bf16(w, x, acc[t], 0, 0, 0);
            }
        }
    }

    unsigned hbf[4][4][2];
#pragma unroll
    for (int t = 0; t < 4; ++t)
#pragma unroll
        for (int Q = 0; Q < 4; ++Q) {
            float h0 = silu(acc[t][4*Q+0]), h1 = silu(acc[t][4*Q+1]);
            float h2 = silu(acc[t][4*Q+2]), h3 = silu(acc[t][4*Q+3]);
            hbf[t][Q][0] = pkbf(h0, h1);
            hbf[t][Q][1] = pkbf(h2, h3);
        }

    f32x16 acc2[4];
#pragma unroll
    for (int tt = 0; tt < 4; ++tt)
#pragma unroll
        for (int r = 0; r < 16; ++r) acc2[tt][r] = bov[tt];

#pragma unroll
    for (int s = 0; s < 8; ++s) {
        const int t  = s >> 1;
        const int q0 = (2 * s) & 3;
        const int q1 = q0 + 1;
        unsigned X0 = hbf[t][q0][0], X1 = hbf[t][q0][1];
        unsigned Y0 = hbf[t][q1][0], Y1 = hbf[t][q1][1];
        plswap(X0, Y0);
        plswap(X1, Y1);
        u32x4 fv = { X0, X1, Y0, Y1 };
        bf16x8 hf = __builtin_bit_cast(bf16x8, fv);
        const short* wb = w2frag + s * 2048 + fslot;
#pragma unroll
        for (int tt = 0; tt < 4; ++tt) {
            bf16x8 w = *(const bf16x8*)(wb + tt * 512);
            acc2[tt] = __builtin_amdgcn_mfma_f32_32x32x16_bf16(hf, w, acc2[tt], 0, 0, 0);
        }
    }

#pragma unroll
    for (int r = 0; r < 16; ++r) {
        float s1 = acc2[0][r] + acc2[1][r] + acc2[2][r] + acc2[3][r];
        float s2 = acc2[0][r]*acc2[0][r] + acc2[1][r]*acc2[1][r]
                 + acc2[2][r]*acc2[2][r] + acc2[3][r]*acc2[3][r];
#pragma unroll
        for (int msk = 1; msk < 32; msk <<= 1) {
            s1 += __shfl_xor(s1, msk, 64);
            s2 += __shfl_xor(s2, msk, 64);
        }
        const float mu   = s1 * (1.0f / 128.0f);
        const float var  = s2 * (1.0f / 128.0f) - mu * mu;
        const float rstd = rsqrtf(var + 1e-5f);
        const int   m    = (r & 3) + 8 * (r >> 2) + 4 * hi;
        const int   eo   = ebase + m;
        if (eo < E) {
            float* po = out + (size_t)eo * DDIM;
#pragma unroll
            for (int tt = 0; tt < 4; ++tt) {
                float o = (acc2[tt][r] - mu) * rstd * gv[tt] + bv[tt];
                po[32 * tt + lo] = o;
            }
        }
    }
}

extern "C" void kernel_launch(void* const* d_in, const int* in_sizes, int n_in,
                              void* d_out, int out_size, void* d_ws, size_t ws_size,
                              hipStream_t stream)
{
    const float* efeat    = (const float*)d_in[0];
    const float* src_feat = (const float*)d_in[1];
    const float* dst_feat = (const float*)d_in[2];
    const int*   src_idx  = (const int*)d_in[3];
    const int*   dst_idx  = (const int*)d_in[4];
    const float* w_efeat  = (const float*)d_in[5];
    const float* w_src    = (const float*)d_in[6];
    const float* w_dst    = (const float*)d_in[7];
    const float* b0       = (const float*)d_in[8];
    const float* w_out    = (const float*)d_in[9];
    const float* b_out    = (const float*)d_in[10];
    const float* ln_g     = (const float*)d_in[11];
    const float* ln_b     = (const float*)d_in[12];
    float* out = (float*)d_out;
    const int E    = in_sizes[3];
    const int nsrc = in_sizes[1] / DDIM;
    const int ndst = in_sizes[2] / DDIM;

    short* w1frag = (short*)d_ws;                              // 96 KB
    short* w2frag = (short*)((char*)d_ws + 24 * 128 * 16 * 2); // 32 KB
    const size_t tab_off  = 128 * 1024;
    const size_t need_tab = tab_off + ((size_t)nsrc + (size_t)ndst) * DDIM * 2;

    prep_weights<<<256, 256, 0, stream>>>(w_efeat, w_src, w_dst, w_out, w1frag, w2frag);

    const int nb = (E + 127) / 128;
    if (ws_size >= need_tab) {
        short* tsrc = (short*)((char*)d_ws + tab_off);
        short* tdst = tsrc + (size_t)nsrc * DDIM;
        node_table<<<(nsrc + 127) / 128, 256, 0, stream>>>(src_feat, w1frag, 8,  tsrc, nsrc);
        node_table<<<(ndst + 127) / 128, 256, 0, stream>>>(dst_feat, w1frag, 16, tdst, ndst);
        edge_kernel_tab<<<nb, 256, 0, stream>>>(efeat, tsrc, tdst, src_idx, dst_idx,
                                                b0, b_out, ln_g, ln_b, w1frag, w2frag, out, E);
    } else {
        edge_kernel_fullk<<<nb, 256, 0, stream>>>(efeat, src_feat, dst_feat, src_idx, dst_idx,
                                                  b0, b_out, ln_g, ln_b, w1frag, w2frag, out, E);
    }
}